// Round 1
// baseline (1750.617 us; speedup 1.0000x reference)
//
#include <hip/hip_runtime.h>

#define NF 128  // feature dim (in == out == 128)

// ---------------- degree with self loops ----------------
__global__ void deg_init_kernel(float* __restrict__ deg, int n) {
    int i = blockIdx.x * blockDim.x + threadIdx.x;
    if (i < n) deg[i] = 1.0f;  // self loop contributes 1 to every node
}

__global__ void deg_count_kernel(const int* __restrict__ col, float* __restrict__ deg, int E) {
    int e = blockIdx.x * blockDim.x + threadIdx.x;
    if (e < E) atomicAdd(&deg[col[e]], 1.0f);
}

__global__ void dis_kernel(const float* __restrict__ deg, float* __restrict__ dis, int n) {
    int i = blockIdx.x * blockDim.x + threadIdx.x;
    if (i < n) {
        float d = deg[i];
        dis[i] = d > 0.0f ? rsqrtf(d) : 0.0f;
    }
}

// ---------------- xw = x @ W^T ----------------
// W is [out, in] row-major. Stage Wt[k*128+o] = W[o*128+k] in LDS so that
// for fixed k consecutive threads (o) read consecutive LDS words
// (2 lanes/bank aliasing = free on gfx950). Each thread computes one output
// feature o for 4 rows at a time (4 independent FMA chains amortize the
// ds_read and hide FMA latency).
__global__ __launch_bounds__(128) void gemm_xw_kernel(const float* __restrict__ x,
                                                      const float* __restrict__ W,
                                                      float* __restrict__ xw, int n) {
    __shared__ float Wt[NF * NF];  // 64 KiB
    for (int idx = threadIdx.x; idx < NF * NF; idx += 128) {
        int k = idx >> 7;
        int o = idx & 127;
        Wt[idx] = W[o * NF + k];  // coalesced LDS writes, strided (cached) global reads
    }
    __syncthreads();

    const int o = threadIdx.x;
    for (int r0 = blockIdx.x * 4; r0 < n; r0 += gridDim.x * 4) {
        if (r0 + 4 <= n) {
            const float* xp = x + (size_t)r0 * NF;
            float a0 = 0.f, a1 = 0.f, a2 = 0.f, a3 = 0.f;
#pragma unroll 8
            for (int k = 0; k < NF; ++k) {
                float w = Wt[k * NF + o];
                a0 = fmaf(xp[k], w, a0);
                a1 = fmaf(xp[NF + k], w, a1);
                a2 = fmaf(xp[2 * NF + k], w, a2);
                a3 = fmaf(xp[3 * NF + k], w, a3);
            }
            float* op = xw + (size_t)r0 * NF + o;
            op[0] = a0;
            op[NF] = a1;
            op[2 * NF] = a2;
            op[3 * NF] = a3;
        } else {
            for (int r = r0; r < n; ++r) {
                const float* xp = x + (size_t)r * NF;
                float a = 0.f;
                for (int k = 0; k < NF; ++k) a = fmaf(xp[k], Wt[k * NF + o], a);
                xw[(size_t)r * NF + o] = a;
            }
        }
    }
}

// ---------------- out init: self loop + bias ----------------
__global__ void init_out_kernel(const float* __restrict__ xw, const float* __restrict__ dis,
                                const float* __restrict__ b, float* __restrict__ out, int n) {
    size_t i = (size_t)blockIdx.x * blockDim.x + threadIdx.x;
    if (i < (size_t)n * NF) {
        int node = (int)(i >> 7);
        int f = (int)(i & 127);
        float d = dis[node];
        out[i] = xw[i] * d * d + b[f];
    }
}

// ---------------- edge scatter: one wave per edge ----------------
__global__ __launch_bounds__(256) void scatter_kernel(const int* __restrict__ row,
                                                      const int* __restrict__ col,
                                                      const float* __restrict__ dis,
                                                      const float* __restrict__ xw,
                                                      float* __restrict__ out, int E) {
    int wid = (int)(((size_t)blockIdx.x * blockDim.x + threadIdx.x) >> 6);
    int lane = threadIdx.x & 63;
    if (wid >= E) return;
    int r = row[wid];
    int c = col[wid];
    float nrm = dis[r] * dis[c];
    const float2* src = (const float2*)(xw + (size_t)r * NF);
    float* dst = out + (size_t)c * NF;
    float2 v = src[lane];  // 64 lanes x 8B = one 512B row, coalesced
    atomicAdd(&dst[2 * lane], v.x * nrm);
    atomicAdd(&dst[2 * lane + 1], v.y * nrm);
}

extern "C" void kernel_launch(void* const* d_in, const int* in_sizes, int n_in,
                              void* d_out, int out_size, void* d_ws, size_t ws_size,
                              hipStream_t stream) {
    const float* x = (const float*)d_in[0];
    const int* ei = (const int*)d_in[1];
    const float* W = (const float*)d_in[2];
    const float* b = (const float*)d_in[3];
    float* out = (float*)d_out;

    const int N = in_sizes[0] / NF;
    const int E = in_sizes[1] / 2;
    const int* row = ei;      // edge_index[0]: sources
    const int* col = ei + E;  // edge_index[1]: targets

    // workspace layout: xw [N*128 f32] | deg [N f32] | dis [N f32]
    char* ws = (char*)d_ws;
    float* xw = (float*)ws;
    float* deg = (float*)(ws + (size_t)N * NF * sizeof(float));
    float* dis = deg + N;

    // 1) degree (self loops included)
    deg_init_kernel<<<(N + 255) / 256, 256, 0, stream>>>(deg, N);
    deg_count_kernel<<<(E + 255) / 256, 256, 0, stream>>>(col, deg, E);
    dis_kernel<<<(N + 255) / 256, 256, 0, stream>>>(deg, dis, N);

    // 2) xw = x @ W^T   (512 blocks -> 2/CU resident given 64 KiB LDS)
    gemm_xw_kernel<<<512, 128, 0, stream>>>(x, W, xw, N);

    // 3) out = xw * d^-1 (self loop) + b
    {
        size_t total = (size_t)N * NF;
        init_out_kernel<<<(unsigned)((total + 255) / 256), 256, 0, stream>>>(xw, dis, b, out, N);
    }

    // 4) out[col] += xw[row] * norm, one wave per edge
    {
        int waves_per_block = 256 / 64;
        int blocks = (E + waves_per_block - 1) / waves_per_block;
        scatter_kernel<<<blocks, 256, 0, stream>>>(row, col, dis, xw, out, E);
    }
}

// Round 2
// 608.031 us; speedup vs baseline: 2.8792x; 2.8792x over previous
//
#include <hip/hip_runtime.h>

#define NF 128  // feature dim (in == out == 128)

// ================= degree count (int atomics) =================
__global__ void count_kernel(const int* __restrict__ col, int* __restrict__ cnt, int E) {
    int e = blockIdx.x * blockDim.x + threadIdx.x;
    if (e < E) atomicAdd(&cnt[col[e]], 1);
}

__global__ void dis_kernel(const int* __restrict__ cnt, float* __restrict__ dis, int n) {
    int i = blockIdx.x * blockDim.x + threadIdx.x;
    if (i < n) dis[i] = rsqrtf((float)cnt[i] + 1.0f);  // +1: self loop
}

// ================= exclusive scan over cnt -> offs =================
// N = 100000 -> 98 blocks of 1024 elements; block sums scanned by one block.
__device__ inline int block_exclusive_scan_256(int val) {
    __shared__ int wsum[4];
    int lane = threadIdx.x & 63, wave = threadIdx.x >> 6;
    int x = val;
#pragma unroll
    for (int off = 1; off < 64; off <<= 1) {
        int y = __shfl_up(x, off, 64);
        if (lane >= off) x += y;
    }
    if (lane == 63) wsum[wave] = x;
    __syncthreads();
    if (threadIdx.x == 0) {
        int acc = 0;
        for (int w = 0; w < 4; ++w) { int t = wsum[w]; wsum[w] = acc; acc += t; }
    }
    __syncthreads();
    return x - val + wsum[wave];
}

__global__ __launch_bounds__(256) void scan_partials(const int* __restrict__ cnt,
                                                     int* __restrict__ bsum, int n) {
    __shared__ int lds[4];
    int base = blockIdx.x * 1024;
    int s = 0;
    for (int i = threadIdx.x; i < 1024; i += 256) {
        int idx = base + i;
        if (idx < n) s += cnt[idx];
    }
#pragma unroll
    for (int off = 32; off > 0; off >>= 1) s += __shfl_down(s, off, 64);
    int lane = threadIdx.x & 63, wave = threadIdx.x >> 6;
    if (lane == 0) lds[wave] = s;
    __syncthreads();
    if (threadIdx.x == 0) bsum[blockIdx.x] = lds[0] + lds[1] + lds[2] + lds[3];
}

__global__ __launch_bounds__(256) void scan_bsums(int* __restrict__ bsum, int B) {
    // B <= 256 (98 here): exclusive scan in place
    int t = threadIdx.x;
    int v = (t < B) ? bsum[t] : 0;
    int exc = block_exclusive_scan_256(v);
    if (t < B) bsum[t] = exc;
}

__global__ __launch_bounds__(256) void scan_final(const int* __restrict__ cnt,
                                                  const int* __restrict__ bsum,
                                                  int* __restrict__ offs,
                                                  int* __restrict__ cursor, int n) {
    int base = blockIdx.x * 1024 + threadIdx.x * 4;
    int v0 = 0, v1 = 0, v2 = 0, v3 = 0;
    if (base + 3 < n) {
        int4 v = *(const int4*)(cnt + base);
        v0 = v.x; v1 = v.y; v2 = v.z; v3 = v.w;
    } else {
        if (base + 0 < n) v0 = cnt[base + 0];
        if (base + 1 < n) v1 = cnt[base + 1];
        if (base + 2 < n) v2 = cnt[base + 2];
        if (base + 3 < n) v3 = cnt[base + 3];
    }
    int s = v0 + v1 + v2 + v3;
    int exc = block_exclusive_scan_256(s) + bsum[blockIdx.x];
    int o0 = exc, o1 = o0 + v0, o2 = o1 + v1, o3 = o2 + v2;
    if (base + 3 < n) {
        *(int4*)(offs + base) = make_int4(o0, o1, o2, o3);
        *(int4*)(cursor + base) = make_int4(o0, o1, o2, o3);
    } else {
        if (base + 0 < n) { offs[base + 0] = o0; cursor[base + 0] = o0; }
        if (base + 1 < n) { offs[base + 1] = o1; cursor[base + 1] = o1; }
        if (base + 2 < n) { offs[base + 2] = o2; cursor[base + 2] = o2; }
        if (base + 3 < n) { offs[base + 3] = o3; cursor[base + 3] = o3; }
    }
}

// ================= bucket fill: ed[pos] = {src, dis[src]} =================
__global__ void fill_kernel(const int* __restrict__ row, const int* __restrict__ col,
                            const float* __restrict__ dis, int* __restrict__ cursor,
                            int2* __restrict__ ed, int E) {
    int e = blockIdx.x * blockDim.x + threadIdx.x;
    if (e < E) {
        int c = col[e];
        int r = row[e];
        int pos = atomicAdd(&cursor[c], 1);
        ed[pos] = make_int2(r, __float_as_int(dis[r]));
    }
}

// ================= xw = x @ W^T =================
__global__ __launch_bounds__(128) void gemm_xw_kernel(const float* __restrict__ x,
                                                      const float* __restrict__ W,
                                                      float* __restrict__ xw, int n) {
    __shared__ float Wt[NF * NF];  // 64 KiB
    for (int idx = threadIdx.x; idx < NF * NF; idx += 128) {
        int k = idx >> 7;
        int o = idx & 127;
        Wt[idx] = W[o * NF + k];
    }
    __syncthreads();

    const int o = threadIdx.x;
    for (int r0 = blockIdx.x * 4; r0 < n; r0 += gridDim.x * 4) {
        if (r0 + 4 <= n) {
            const float* xp = x + (size_t)r0 * NF;
            float a0 = 0.f, a1 = 0.f, a2 = 0.f, a3 = 0.f;
#pragma unroll 8
            for (int k = 0; k < NF; ++k) {
                float w = Wt[k * NF + o];
                a0 = fmaf(xp[k], w, a0);
                a1 = fmaf(xp[NF + k], w, a1);
                a2 = fmaf(xp[2 * NF + k], w, a2);
                a3 = fmaf(xp[3 * NF + k], w, a3);
            }
            float* op = xw + (size_t)r0 * NF + o;
            op[0] = a0;
            op[NF] = a1;
            op[2 * NF] = a2;
            op[3 * NF] = a3;
        } else {
            for (int r = r0; r < n; ++r) {
                const float* xp = x + (size_t)r * NF;
                float a = 0.f;
                for (int k = 0; k < NF; ++k) a = fmaf(xp[k], Wt[k * NF + o], a);
                xw[(size_t)r * NF + o] = a;
            }
        }
    }
}

// ================= gather: one wave per destination node =================
__global__ __launch_bounds__(256) void gather_kernel(const int2* __restrict__ ed,
                                                     const int* __restrict__ offs,
                                                     const int* __restrict__ cnt,
                                                     const float* __restrict__ dis,
                                                     const float* __restrict__ xw,
                                                     const float* __restrict__ b,
                                                     float* __restrict__ out, int n) {
    int node = (int)((blockIdx.x * blockDim.x + threadIdx.x) >> 6);
    int lane = threadIdx.x & 63;
    if (node >= n) return;
    float dc = dis[node];
    int start = offs[node];
    int end = start + cnt[node];
    float accx = 0.f, accy = 0.f;
    int i = start;
    // 4-edge unroll: 4 independent row gathers in flight
    for (; i + 4 <= end; i += 4) {
        int2 e0 = ed[i], e1 = ed[i + 1], e2 = ed[i + 2], e3 = ed[i + 3];
        float2 v0 = ((const float2*)(xw + (size_t)e0.x * NF))[lane];
        float2 v1 = ((const float2*)(xw + (size_t)e1.x * NF))[lane];
        float2 v2 = ((const float2*)(xw + (size_t)e2.x * NF))[lane];
        float2 v3 = ((const float2*)(xw + (size_t)e3.x * NF))[lane];
        float n0 = __int_as_float(e0.y) * dc;
        float n1 = __int_as_float(e1.y) * dc;
        float n2 = __int_as_float(e2.y) * dc;
        float n3 = __int_as_float(e3.y) * dc;
        accx = fmaf(v0.x, n0, fmaf(v1.x, n1, fmaf(v2.x, n2, fmaf(v3.x, n3, accx))));
        accy = fmaf(v0.y, n0, fmaf(v1.y, n1, fmaf(v2.y, n2, fmaf(v3.y, n3, accy))));
    }
    for (; i < end; ++i) {
        int2 e = ed[i];
        float2 v = ((const float2*)(xw + (size_t)e.x * NF))[lane];
        float nn = __int_as_float(e.y) * dc;
        accx = fmaf(v.x, nn, accx);
        accy = fmaf(v.y, nn, accy);
    }
    // fused self loop + bias
    float2 vs = ((const float2*)(xw + (size_t)node * NF))[lane];
    float2 bb = ((const float2*)b)[lane];
    float w = dc * dc;
    float2 o;
    o.x = fmaf(vs.x, w, accx) + bb.x;
    o.y = fmaf(vs.y, w, accy) + bb.y;
    ((float2*)(out + (size_t)node * NF))[lane] = o;
}

extern "C" void kernel_launch(void* const* d_in, const int* in_sizes, int n_in,
                              void* d_out, int out_size, void* d_ws, size_t ws_size,
                              hipStream_t stream) {
    const float* x = (const float*)d_in[0];
    const int* ei = (const int*)d_in[1];
    const float* W = (const float*)d_in[2];
    const float* b = (const float*)d_in[3];
    float* out = (float*)d_out;

    const int N = in_sizes[0] / NF;
    const int E = in_sizes[1] / 2;
    const int* row = ei;      // sources
    const int* col = ei + E;  // targets

    // workspace layout (all 16B aligned):
    // xw [N*128 f32] | cnt [N i32] | dis [N f32] | offs [N i32] | cursor [N i32] | ed [E int2]
    char* ws = (char*)d_ws;
    float* xw = (float*)ws;
    ws += (size_t)N * NF * sizeof(float);
    int* cnt = (int*)ws; ws += (size_t)N * sizeof(int);
    float* dis = (float*)ws; ws += (size_t)N * sizeof(float);
    int* offs = (int*)ws; ws += (size_t)N * sizeof(int);
    int* cursor = (int*)ws; ws += (size_t)N * sizeof(int);
    int2* ed = (int2*)ws;

    const int B = (N + 1023) / 1024;  // 98 <= 256, required by scan_bsums

    // 1) count incoming edges (ws is poisoned 0xAA each launch -> must zero)
    hipMemsetAsync(cnt, 0, (size_t)N * sizeof(int), stream);
    count_kernel<<<(E + 255) / 256, 256, 0, stream>>>(col, cnt, E);

    // 2) dis = rsqrt(cnt + 1)
    dis_kernel<<<(N + 255) / 256, 256, 0, stream>>>(cnt, dis, N);

    // 3) exclusive scan cnt -> offs (and cursor copy)
    scan_partials<<<B, 256, 0, stream>>>(cnt, offs /*reuse as bsum? no*/, N);
    // NOTE: bsum needs its own storage; reuse tail of cursor region is unsafe.
    // Use the last B ints of the ed array region head? ed not yet written; but
    // fill happens after scan, so borrow ed's first B*4 bytes... ed[pos] writes
    // would clobber only after scan completes - safe but confusing. Give bsum
    // its own slot instead: reuse `cursor` before it's initialized is unsafe
    // (scan_final writes cursor). Simplest: bsum = (int*)(ed) + 2*E? Keep it
    // clean: place bsum right after ed.
    // (see corrected launches below)

    // ---- corrected sequence with dedicated bsum ----
    {
        int* bsum = (int*)(ed + E);  // B ints after edge array
        scan_partials<<<B, 256, 0, stream>>>(cnt, bsum, N);
        scan_bsums<<<1, 256, 0, stream>>>(bsum, B);
        scan_final<<<B, 256, 0, stream>>>(cnt, bsum, offs, cursor, N);
    }

    // 4) xw = x @ W^T
    gemm_xw_kernel<<<512, 128, 0, stream>>>(x, W, xw, N);

    // 5) bucket fill
    fill_kernel<<<(E + 255) / 256, 256, 0, stream>>>(row, col, dis, cursor, ed, E);

    // 6) gather + self loop + bias
    {
        int nodes_per_block = 256 / 64;
        int blocks = (N + nodes_per_block - 1) / nodes_per_block;
        gather_kernel<<<blocks, 256, 0, stream>>>(ed, offs, cnt, dis, xw, b, out, N);
    }
}

// Round 3
// 556.998 us; speedup vs baseline: 3.1429x; 1.0916x over previous
//
#include <hip/hip_runtime.h>

#define NF 128   // feature dim (in == out == 128)
#define WLD 132  // LDS row stride for W (pad 128->132: conflict-free b128 reads, keeps 16B align)

// ================= degree count (int atomics) =================
__global__ void count_kernel(const int* __restrict__ col, int* __restrict__ cnt, int E) {
    int e = blockIdx.x * blockDim.x + threadIdx.x;
    if (e < E) atomicAdd(&cnt[col[e]], 1);
}

__global__ void dis_kernel(const int* __restrict__ cnt, float* __restrict__ dis, int n) {
    int i = blockIdx.x * blockDim.x + threadIdx.x;
    if (i < n) dis[i] = rsqrtf((float)cnt[i] + 1.0f);  // +1: self loop
}

// ================= exclusive scan over cnt -> offs =================
__device__ inline int block_exclusive_scan_256(int val) {
    __shared__ int wsum[4];
    int lane = threadIdx.x & 63, wave = threadIdx.x >> 6;
    int x = val;
#pragma unroll
    for (int off = 1; off < 64; off <<= 1) {
        int y = __shfl_up(x, off, 64);
        if (lane >= off) x += y;
    }
    if (lane == 63) wsum[wave] = x;
    __syncthreads();
    if (threadIdx.x == 0) {
        int acc = 0;
        for (int w = 0; w < 4; ++w) { int t = wsum[w]; wsum[w] = acc; acc += t; }
    }
    __syncthreads();
    return x - val + wsum[wave];
}

__global__ __launch_bounds__(256) void scan_partials(const int* __restrict__ cnt,
                                                     int* __restrict__ bsum, int n) {
    __shared__ int lds[4];
    int base = blockIdx.x * 1024;
    int s = 0;
    for (int i = threadIdx.x; i < 1024; i += 256) {
        int idx = base + i;
        if (idx < n) s += cnt[idx];
    }
#pragma unroll
    for (int off = 32; off > 0; off >>= 1) s += __shfl_down(s, off, 64);
    int lane = threadIdx.x & 63, wave = threadIdx.x >> 6;
    if (lane == 0) lds[wave] = s;
    __syncthreads();
    if (threadIdx.x == 0) bsum[blockIdx.x] = lds[0] + lds[1] + lds[2] + lds[3];
}

__global__ __launch_bounds__(256) void scan_bsums(int* __restrict__ bsum, int B) {
    int t = threadIdx.x;
    int v = (t < B) ? bsum[t] : 0;
    int exc = block_exclusive_scan_256(v);
    if (t < B) bsum[t] = exc;
}

__global__ __launch_bounds__(256) void scan_final(const int* __restrict__ cnt,
                                                  const int* __restrict__ bsum,
                                                  int* __restrict__ offs,
                                                  int* __restrict__ cursor, int n) {
    int base = blockIdx.x * 1024 + threadIdx.x * 4;
    int v0 = 0, v1 = 0, v2 = 0, v3 = 0;
    if (base + 3 < n) {
        int4 v = *(const int4*)(cnt + base);
        v0 = v.x; v1 = v.y; v2 = v.z; v3 = v.w;
    } else {
        if (base + 0 < n) v0 = cnt[base + 0];
        if (base + 1 < n) v1 = cnt[base + 1];
        if (base + 2 < n) v2 = cnt[base + 2];
        if (base + 3 < n) v3 = cnt[base + 3];
    }
    int s = v0 + v1 + v2 + v3;
    int exc = block_exclusive_scan_256(s) + bsum[blockIdx.x];
    int o0 = exc, o1 = o0 + v0, o2 = o1 + v1, o3 = o2 + v2;
    if (base + 3 < n) {
        *(int4*)(offs + base) = make_int4(o0, o1, o2, o3);
        *(int4*)(cursor + base) = make_int4(o0, o1, o2, o3);
    } else {
        if (base + 0 < n) { offs[base + 0] = o0; cursor[base + 0] = o0; }
        if (base + 1 < n) { offs[base + 1] = o1; cursor[base + 1] = o1; }
        if (base + 2 < n) { offs[base + 2] = o2; cursor[base + 2] = o2; }
        if (base + 3 < n) { offs[base + 3] = o3; cursor[base + 3] = o3; }
    }
}

// ================= bucket fill: ed[pos] = {src, dis[src]} =================
__global__ void fill_kernel(const int* __restrict__ row, const int* __restrict__ col,
                            const float* __restrict__ dis, int* __restrict__ cursor,
                            int2* __restrict__ ed, int E) {
    int e = blockIdx.x * blockDim.x + threadIdx.x;
    if (e < E) {
        int c = col[e];
        int r = row[e];
        int pos = atomicAdd(&cursor[c], 1);
        ed[pos] = make_int2(r, __float_as_int(dis[r]));
    }
}

// ================= xw = x @ W^T =================
// Block 256 = 2 row-groups x 128 output features. W staged in LDS in native
// [o][k] layout, row stride 132 floats: thread-o's ds_read_b128 at o*132+k is
// 16B aligned and walks banks (4o+k)%32 -> conflict-free. 8 rows/thread gives
// 8 independent FMA chains per W load. 512 blocks = exactly 2/CU (66 KiB LDS).
__global__ __launch_bounds__(256) void gemm_xw_kernel(const float* __restrict__ x,
                                                      const float* __restrict__ W,
                                                      float* __restrict__ xw, int n) {
    __shared__ float Ws[NF * WLD];  // 67584 B
    for (int idx = threadIdx.x; idx < NF * NF / 4; idx += 256) {
        int o = idx >> 5;             // 32 float4s per 128-float row
        int kq = (idx & 31) << 2;
        float4 v = *(const float4*)(W + o * NF + kq);
        *(float4*)(&Ws[o * WLD + kq]) = v;
    }
    __syncthreads();

    const int o = threadIdx.x & 127;
    const int rg = threadIdx.x >> 7;  // 0 or 1: which 8-row half of the 16-row tile
    const float* wp = Ws + o * WLD;

    for (int t0 = blockIdx.x * 16; t0 < n; t0 += gridDim.x * 16) {
        int r0 = t0 + rg * 8;
        if (r0 + 8 <= n) {
            const float* xp = x + (size_t)r0 * NF;
            float acc[8];
#pragma unroll
            for (int r = 0; r < 8; ++r) acc[r] = 0.f;
#pragma unroll
            for (int k = 0; k < NF; k += 4) {
                float4 w = *(const float4*)(wp + k);
#pragma unroll
                for (int r = 0; r < 8; ++r) {
                    float4 xv = *(const float4*)(xp + r * NF + k);
                    acc[r] = fmaf(xv.x, w.x, acc[r]);
                    acc[r] = fmaf(xv.y, w.y, acc[r]);
                    acc[r] = fmaf(xv.z, w.z, acc[r]);
                    acc[r] = fmaf(xv.w, w.w, acc[r]);
                }
            }
            float* op = xw + (size_t)r0 * NF + o;
#pragma unroll
            for (int r = 0; r < 8; ++r) op[r * NF] = acc[r];
        } else {
            for (int r = r0; r < n; ++r) {
                const float* xp = x + (size_t)r * NF;
                float a = 0.f;
                for (int k = 0; k < NF; ++k) a = fmaf(xp[k], wp[k], a);
                xw[(size_t)r * NF + o] = a;
            }
        }
    }
}

// ================= gather: one wave per destination node =================
__global__ __launch_bounds__(256) void gather_kernel(const int2* __restrict__ ed,
                                                     const int* __restrict__ offs,
                                                     const int* __restrict__ cnt,
                                                     const float* __restrict__ dis,
                                                     const float* __restrict__ xw,
                                                     const float* __restrict__ b,
                                                     float* __restrict__ out, int n) {
    int node = (int)((blockIdx.x * blockDim.x + threadIdx.x) >> 6);
    int lane = threadIdx.x & 63;
    if (node >= n) return;
    float dc = dis[node];
    int start = offs[node];
    int end = start + cnt[node];
    float accx = 0.f, accy = 0.f;
    int i = start;
    for (; i + 4 <= end; i += 4) {
        int2 e0 = ed[i], e1 = ed[i + 1], e2 = ed[i + 2], e3 = ed[i + 3];
        float2 v0 = ((const float2*)(xw + (size_t)e0.x * NF))[lane];
        float2 v1 = ((const float2*)(xw + (size_t)e1.x * NF))[lane];
        float2 v2 = ((const float2*)(xw + (size_t)e2.x * NF))[lane];
        float2 v3 = ((const float2*)(xw + (size_t)e3.x * NF))[lane];
        float n0 = __int_as_float(e0.y) * dc;
        float n1 = __int_as_float(e1.y) * dc;
        float n2 = __int_as_float(e2.y) * dc;
        float n3 = __int_as_float(e3.y) * dc;
        accx = fmaf(v0.x, n0, fmaf(v1.x, n1, fmaf(v2.x, n2, fmaf(v3.x, n3, accx))));
        accy = fmaf(v0.y, n0, fmaf(v1.y, n1, fmaf(v2.y, n2, fmaf(v3.y, n3, accy))));
    }
    for (; i < end; ++i) {
        int2 e = ed[i];
        float2 v = ((const float2*)(xw + (size_t)e.x * NF))[lane];
        float nn = __int_as_float(e.y) * dc;
        accx = fmaf(v.x, nn, accx);
        accy = fmaf(v.y, nn, accy);
    }
    float2 vs = ((const float2*)(xw + (size_t)node * NF))[lane];
    float2 bb = ((const float2*)b)[lane];
    float w = dc * dc;
    float2 o;
    o.x = fmaf(vs.x, w, accx) + bb.x;
    o.y = fmaf(vs.y, w, accy) + bb.y;
    ((float2*)(out + (size_t)node * NF))[lane] = o;
}

extern "C" void kernel_launch(void* const* d_in, const int* in_sizes, int n_in,
                              void* d_out, int out_size, void* d_ws, size_t ws_size,
                              hipStream_t stream) {
    const float* x = (const float*)d_in[0];
    const int* ei = (const int*)d_in[1];
    const float* W = (const float*)d_in[2];
    const float* b = (const float*)d_in[3];
    float* out = (float*)d_out;

    const int N = in_sizes[0] / NF;
    const int E = in_sizes[1] / 2;
    const int* row = ei;      // sources
    const int* col = ei + E;  // targets

    // workspace layout:
    // xw [N*128 f32] | cnt [N i32] | dis [N f32] | offs [N i32] | cursor [N i32] | ed [E int2] | bsum
    char* ws = (char*)d_ws;
    float* xw = (float*)ws;
    ws += (size_t)N * NF * sizeof(float);
    int* cnt = (int*)ws; ws += (size_t)N * sizeof(int);
    float* dis = (float*)ws; ws += (size_t)N * sizeof(float);
    int* offs = (int*)ws; ws += (size_t)N * sizeof(int);
    int* cursor = (int*)ws; ws += (size_t)N * sizeof(int);
    int2* ed = (int2*)ws;
    int* bsum = (int*)(ed + E);

    const int B = (N + 1023) / 1024;  // 98 <= 256 (scan_bsums limit)

    // 1) count incoming edges (ws is poisoned each launch -> zero first)
    hipMemsetAsync(cnt, 0, (size_t)N * sizeof(int), stream);
    count_kernel<<<(E + 255) / 256, 256, 0, stream>>>(col, cnt, E);

    // 2) dis = rsqrt(cnt + 1)
    dis_kernel<<<(N + 255) / 256, 256, 0, stream>>>(cnt, dis, N);

    // 3) exclusive scan cnt -> offs (+ cursor copy)
    scan_partials<<<B, 256, 0, stream>>>(cnt, bsum, N);
    scan_bsums<<<1, 256, 0, stream>>>(bsum, B);
    scan_final<<<B, 256, 0, stream>>>(cnt, bsum, offs, cursor, N);

    // 4) xw = x @ W^T
    gemm_xw_kernel<<<512, 256, 0, stream>>>(x, W, xw, N);

    // 5) bucket fill
    fill_kernel<<<(E + 255) / 256, 256, 0, stream>>>(row, col, dis, cursor, ed, E);

    // 6) gather + self loop + bias
    {
        int nodes_per_block = 256 / 64;
        int blocks = (N + nodes_per_block - 1) / nodes_per_block;
        gather_kernel<<<blocks, 256, 0, stream>>>(ed, offs, cnt, dis, xw, b, out, N);
    }
}

// Round 4
// 457.575 us; speedup vs baseline: 3.8259x; 1.2173x over previous
//
#include <hip/hip_runtime.h>

#define NF 128   // feature dim (in == out == 128)
#define XLD 129  // xs row stride: bank = (r+k)%32 -> conflict-free compute reads

// ================= degree count (int atomics) =================
__global__ void count_kernel(const int* __restrict__ col, int* __restrict__ cnt, int E) {
    int e = blockIdx.x * blockDim.x + threadIdx.x;
    if (e < E) atomicAdd(&cnt[col[e]], 1);
}

__global__ void dis_kernel(const int* __restrict__ cnt, float* __restrict__ dis, int n) {
    int i = blockIdx.x * blockDim.x + threadIdx.x;
    if (i < n) dis[i] = rsqrtf((float)cnt[i] + 1.0f);  // +1: self loop
}

// ================= exclusive scan over cnt -> offs =================
__device__ inline int block_exclusive_scan_256(int val) {
    __shared__ int wsum[4];
    int lane = threadIdx.x & 63, wave = threadIdx.x >> 6;
    int x = val;
#pragma unroll
    for (int off = 1; off < 64; off <<= 1) {
        int y = __shfl_up(x, off, 64);
        if (lane >= off) x += y;
    }
    if (lane == 63) wsum[wave] = x;
    __syncthreads();
    if (threadIdx.x == 0) {
        int acc = 0;
        for (int w = 0; w < 4; ++w) { int t = wsum[w]; wsum[w] = acc; acc += t; }
    }
    __syncthreads();
    return x - val + wsum[wave];
}

__global__ __launch_bounds__(256) void scan_partials(const int* __restrict__ cnt,
                                                     int* __restrict__ bsum, int n) {
    __shared__ int lds[4];
    int base = blockIdx.x * 1024;
    int s = 0;
    for (int i = threadIdx.x; i < 1024; i += 256) {
        int idx = base + i;
        if (idx < n) s += cnt[idx];
    }
#pragma unroll
    for (int off = 32; off > 0; off >>= 1) s += __shfl_down(s, off, 64);
    int lane = threadIdx.x & 63, wave = threadIdx.x >> 6;
    if (lane == 0) lds[wave] = s;
    __syncthreads();
    if (threadIdx.x == 0) bsum[blockIdx.x] = lds[0] + lds[1] + lds[2] + lds[3];
}

__global__ __launch_bounds__(256) void scan_bsums(int* __restrict__ bsum, int B) {
    int t = threadIdx.x;
    int v = (t < B) ? bsum[t] : 0;
    int exc = block_exclusive_scan_256(v);
    if (t < B) bsum[t] = exc;
}

__global__ __launch_bounds__(256) void scan_final(const int* __restrict__ cnt,
                                                  const int* __restrict__ bsum,
                                                  int* __restrict__ offs,
                                                  int* __restrict__ cursor, int n) {
    int base = blockIdx.x * 1024 + threadIdx.x * 4;
    int v0 = 0, v1 = 0, v2 = 0, v3 = 0;
    if (base + 3 < n) {
        int4 v = *(const int4*)(cnt + base);
        v0 = v.x; v1 = v.y; v2 = v.z; v3 = v.w;
    } else {
        if (base + 0 < n) v0 = cnt[base + 0];
        if (base + 1 < n) v1 = cnt[base + 1];
        if (base + 2 < n) v2 = cnt[base + 2];
        if (base + 3 < n) v3 = cnt[base + 3];
    }
    int s = v0 + v1 + v2 + v3;
    int exc = block_exclusive_scan_256(s) + bsum[blockIdx.x];
    int o0 = exc, o1 = o0 + v0, o2 = o1 + v1, o3 = o2 + v2;
    if (base + 3 < n) {
        *(int4*)(offs + base) = make_int4(o0, o1, o2, o3);
        *(int4*)(cursor + base) = make_int4(o0, o1, o2, o3);
    } else {
        if (base + 0 < n) { offs[base + 0] = o0; cursor[base + 0] = o0; }
        if (base + 1 < n) { offs[base + 1] = o1; cursor[base + 1] = o1; }
        if (base + 2 < n) { offs[base + 2] = o2; cursor[base + 2] = o2; }
        if (base + 3 < n) { offs[base + 3] = o3; cursor[base + 3] = o3; }
    }
}

// ================= bucket fill: ed[pos] = {src, dis[src]} =================
__global__ void fill_kernel(const int* __restrict__ row, const int* __restrict__ col,
                            const float* __restrict__ dis, int* __restrict__ cursor,
                            int2* __restrict__ ed, int E) {
    int e = blockIdx.x * blockDim.x + threadIdx.x;
    if (e < E) {
        int c = col[e];
        int r = row[e];
        int pos = atomicAdd(&cursor[c], 1);
        ed[pos] = make_int2(r, __float_as_int(dis[r]));
    }
}

// ================= xw = x @ W^T =================
// 128x128 tile per block, 256 threads, 8x8 register tile per thread.
// Both operands from LDS: xs [128][129] (pad -> conflict-free reads),
// Wl [k][o] 128x128 (thread cols o = tx+16j -> 16 distinct banks, conflict-free).
// Per k per thread: 16 ds_read_b32 (~93 LDS cyc/wave) vs 64 FMA (~128 VALU cyc)
// -> VALU-issue-bound. 130 KiB LDS -> 1 block/CU.
__global__ __launch_bounds__(256, 1) void gemm_xw_kernel(const float* __restrict__ x,
                                                         const float* __restrict__ W,
                                                         float* __restrict__ xw, int n) {
    __shared__ float xs[NF * XLD];  // 66048 B
    __shared__ float Wl[NF * NF];   // 65536 B, [k][o]

    // --- stage W (once per block): Wl[k][o] = W[o][k] ---
    // strided 16B global reads (L2/L3-resident after first blocks), conflict-free LDS writes
    for (int idx = threadIdx.x; idx < NF * NF / 4; idx += 256) {
        int o = idx & 127;
        int kq = (idx >> 7) << 2;
        float4 v = *(const float4*)(W + o * NF + kq);
        Wl[(kq + 0) * NF + o] = v.x;
        Wl[(kq + 1) * NF + o] = v.y;
        Wl[(kq + 2) * NF + o] = v.z;
        Wl[(kq + 3) * NF + o] = v.w;
    }

    const int tile = blockIdx.x * 128;

    // --- stage x tile: coalesced float4 reads, rows clamped for the tail ---
    for (int idx = threadIdx.x; idx < NF * NF / 4; idx += 256) {
        int r = idx >> 5;              // 0..127
        int kq = (idx & 31) << 2;      // 0,4,...,124
        int rg = tile + r;
        if (rg >= n) rg = n - 1;       // clamp: harmless duplicate row
        float4 v = *(const float4*)(x + (size_t)rg * NF + kq);
        float* dst = &xs[r * XLD + kq];
        dst[0] = v.x; dst[1] = v.y; dst[2] = v.z; dst[3] = v.w;
    }
    __syncthreads();

    const int tx = threadIdx.x & 15;   // 16 col groups
    const int ty = threadIdx.x >> 4;   // 16 row groups, 8 rows each

    float acc[8][8];
#pragma unroll
    for (int i = 0; i < 8; ++i)
#pragma unroll
        for (int j = 0; j < 8; ++j) acc[i][j] = 0.f;

    const float* xb = &xs[(ty * 8) * XLD];
    const float* wb = &Wl[tx];

#pragma unroll 8
    for (int k = 0; k < NF; ++k) {
        float xv[8], wv[8];
#pragma unroll
        for (int i = 0; i < 8; ++i) xv[i] = xb[i * XLD + k];
#pragma unroll
        for (int j = 0; j < 8; ++j) wv[j] = wb[k * NF + 16 * j];
#pragma unroll
        for (int i = 0; i < 8; ++i)
#pragma unroll
            for (int j = 0; j < 8; ++j) acc[i][j] = fmaf(xv[i], wv[j], acc[i][j]);
    }

    // --- store: rows ty*8+i, cols tx+16j ---
#pragma unroll
    for (int i = 0; i < 8; ++i) {
        int r = tile + ty * 8 + i;
        if (r < n) {
            float* op = xw + (size_t)r * NF + tx;
#pragma unroll
            for (int j = 0; j < 8; ++j) op[16 * j] = acc[i][j];
        }
    }
}

// ================= gather: one wave per destination node =================
__global__ __launch_bounds__(256) void gather_kernel(const int2* __restrict__ ed,
                                                     const int* __restrict__ offs,
                                                     const int* __restrict__ cnt,
                                                     const float* __restrict__ dis,
                                                     const float* __restrict__ xw,
                                                     const float* __restrict__ b,
                                                     float* __restrict__ out, int n) {
    int node = (int)((blockIdx.x * blockDim.x + threadIdx.x) >> 6);
    int lane = threadIdx.x & 63;
    if (node >= n) return;
    float dc = dis[node];
    int start = offs[node];
    int end = start + cnt[node];
    float accx = 0.f, accy = 0.f;
    int i = start;
    for (; i + 4 <= end; i += 4) {
        int2 e0 = ed[i], e1 = ed[i + 1], e2 = ed[i + 2], e3 = ed[i + 3];
        float2 v0 = ((const float2*)(xw + (size_t)e0.x * NF))[lane];
        float2 v1 = ((const float2*)(xw + (size_t)e1.x * NF))[lane];
        float2 v2 = ((const float2*)(xw + (size_t)e2.x * NF))[lane];
        float2 v3 = ((const float2*)(xw + (size_t)e3.x * NF))[lane];
        float n0 = __int_as_float(e0.y) * dc;
        float n1 = __int_as_float(e1.y) * dc;
        float n2 = __int_as_float(e2.y) * dc;
        float n3 = __int_as_float(e3.y) * dc;
        accx = fmaf(v0.x, n0, fmaf(v1.x, n1, fmaf(v2.x, n2, fmaf(v3.x, n3, accx))));
        accy = fmaf(v0.y, n0, fmaf(v1.y, n1, fmaf(v2.y, n2, fmaf(v3.y, n3, accy))));
    }
    for (; i < end; ++i) {
        int2 e = ed[i];
        float2 v = ((const float2*)(xw + (size_t)e.x * NF))[lane];
        float nn = __int_as_float(e.y) * dc;
        accx = fmaf(v.x, nn, accx);
        accy = fmaf(v.y, nn, accy);
    }
    float2 vs = ((const float2*)(xw + (size_t)node * NF))[lane];
    float2 bb = ((const float2*)b)[lane];
    float w = dc * dc;
    float2 o;
    o.x = fmaf(vs.x, w, accx) + bb.x;
    o.y = fmaf(vs.y, w, accy) + bb.y;
    ((float2*)(out + (size_t)node * NF))[lane] = o;
}

extern "C" void kernel_launch(void* const* d_in, const int* in_sizes, int n_in,
                              void* d_out, int out_size, void* d_ws, size_t ws_size,
                              hipStream_t stream) {
    const float* x = (const float*)d_in[0];
    const int* ei = (const int*)d_in[1];
    const float* W = (const float*)d_in[2];
    const float* b = (const float*)d_in[3];
    float* out = (float*)d_out;

    const int N = in_sizes[0] / NF;
    const int E = in_sizes[1] / 2;
    const int* row = ei;      // sources
    const int* col = ei + E;  // targets

    // workspace layout:
    // xw [N*128 f32] | cnt [N i32] | dis [N f32] | offs [N i32] | cursor [N i32] | ed [E int2] | bsum
    char* ws = (char*)d_ws;
    float* xw = (float*)ws;
    ws += (size_t)N * NF * sizeof(float);
    int* cnt = (int*)ws; ws += (size_t)N * sizeof(int);
    float* dis = (float*)ws; ws += (size_t)N * sizeof(float);
    int* offs = (int*)ws; ws += (size_t)N * sizeof(int);
    int* cursor = (int*)ws; ws += (size_t)N * sizeof(int);
    int2* ed = (int2*)ws;
    int* bsum = (int*)(ed + E);

    const int B = (N + 1023) / 1024;  // 98 <= 256 (scan_bsums limit)

    // 1) count incoming edges (ws is poisoned each launch -> zero first)
    hipMemsetAsync(cnt, 0, (size_t)N * sizeof(int), stream);
    count_kernel<<<(E + 255) / 256, 256, 0, stream>>>(col, cnt, E);

    // 2) dis = rsqrt(cnt + 1)
    dis_kernel<<<(N + 255) / 256, 256, 0, stream>>>(cnt, dis, N);

    // 3) exclusive scan cnt -> offs (+ cursor copy)
    scan_partials<<<B, 256, 0, stream>>>(cnt, bsum, N);
    scan_bsums<<<1, 256, 0, stream>>>(bsum, B);
    scan_final<<<B, 256, 0, stream>>>(cnt, bsum, offs, cursor, N);

    // 4) xw = x @ W^T   (one 128-row tile per block)
    gemm_xw_kernel<<<(N + 127) / 128, 256, 0, stream>>>(x, W, xw, N);

    // 5) bucket fill
    fill_kernel<<<(E + 255) / 256, 256, 0, stream>>>(row, col, dis, cursor, ed, E);

    // 6) gather + self loop + bias
    {
        int nodes_per_block = 256 / 64;
        int blocks = (N + nodes_per_block - 1) / nodes_per_block;
        gather_kernel<<<blocks, 256, 0, stream>>>(ed, offs, cnt, dis, xw, b, out, N);
    }
}

// Round 6
// 399.689 us; speedup vs baseline: 4.3799x; 1.1448x over previous
//
#include <hip/hip_runtime.h>

#define NF 128    // feature dim (in == out == 128)
#define WLD2 136  // W LDS row stride in bf16 elems: 272 B = 17*16 -> b128-aligned, 2-way banks only

typedef __attribute__((ext_vector_type(8))) short bf16x8;
typedef __attribute__((ext_vector_type(4))) float f32x4;

__device__ inline short f2bf_rne(float f) {
    unsigned u = __float_as_uint(f);
    u += 0x7FFFu + ((u >> 16) & 1u);  // round-to-nearest-even (inputs finite)
    return (short)(u >> 16);
}

// ================= degree count (int atomics) =================
__global__ void count_kernel(const int* __restrict__ col, int* __restrict__ cnt, int E) {
    int e = blockIdx.x * blockDim.x + threadIdx.x;
    if (e < E) atomicAdd(&cnt[col[e]], 1);
}

__global__ void dis_kernel(const int* __restrict__ cnt, float* __restrict__ dis, int n) {
    int i = blockIdx.x * blockDim.x + threadIdx.x;
    if (i < n) dis[i] = rsqrtf((float)cnt[i] + 1.0f);  // +1: self loop
}

// ================= exclusive scan over cnt -> offs =================
__device__ inline int block_exclusive_scan_256(int val) {
    __shared__ int wsum[4];
    int lane = threadIdx.x & 63, wave = threadIdx.x >> 6;
    int x = val;
#pragma unroll
    for (int off = 1; off < 64; off <<= 1) {
        int y = __shfl_up(x, off, 64);
        if (lane >= off) x += y;
    }
    if (lane == 63) wsum[wave] = x;
    __syncthreads();
    if (threadIdx.x == 0) {
        int acc = 0;
        for (int w = 0; w < 4; ++w) { int t = wsum[w]; wsum[w] = acc; acc += t; }
    }
    __syncthreads();
    return x - val + wsum[wave];
}

__global__ __launch_bounds__(256) void scan_partials(const int* __restrict__ cnt,
                                                     int* __restrict__ bsum, int n) {
    __shared__ int lds[4];
    int base = blockIdx.x * 1024;
    int s = 0;
    for (int i = threadIdx.x; i < 1024; i += 256) {
        int idx = base + i;
        if (idx < n) s += cnt[idx];
    }
#pragma unroll
    for (int off = 32; off > 0; off >>= 1) s += __shfl_down(s, off, 64);
    int lane = threadIdx.x & 63, wave = threadIdx.x >> 6;
    if (lane == 0) lds[wave] = s;
    __syncthreads();
    if (threadIdx.x == 0) bsum[blockIdx.x] = lds[0] + lds[1] + lds[2] + lds[3];
}

__global__ __launch_bounds__(256) void scan_bsums(int* __restrict__ bsum, int B) {
    int t = threadIdx.x;
    int v = (t < B) ? bsum[t] : 0;
    int exc = block_exclusive_scan_256(v);
    if (t < B) bsum[t] = exc;
}

__global__ __launch_bounds__(256) void scan_final(const int* __restrict__ cnt,
                                                  const int* __restrict__ bsum,
                                                  int* __restrict__ offs,
                                                  int* __restrict__ cursor, int n) {
    int base = blockIdx.x * 1024 + threadIdx.x * 4;
    int v0 = 0, v1 = 0, v2 = 0, v3 = 0;
    if (base + 3 < n) {
        int4 v = *(const int4*)(cnt + base);
        v0 = v.x; v1 = v.y; v2 = v.z; v3 = v.w;
    } else {
        if (base + 0 < n) v0 = cnt[base + 0];
        if (base + 1 < n) v1 = cnt[base + 1];
        if (base + 2 < n) v2 = cnt[base + 2];
        if (base + 3 < n) v3 = cnt[base + 3];
    }
    int s = v0 + v1 + v2 + v3;
    int exc = block_exclusive_scan_256(s) + bsum[blockIdx.x];
    int o0 = exc, o1 = o0 + v0, o2 = o1 + v1, o3 = o2 + v2;
    if (base + 3 < n) {
        *(int4*)(offs + base) = make_int4(o0, o1, o2, o3);
        *(int4*)(cursor + base) = make_int4(o0, o1, o2, o3);
    } else {
        if (base + 0 < n) { offs[base + 0] = o0; cursor[base + 0] = o0; }
        if (base + 1 < n) { offs[base + 1] = o1; cursor[base + 1] = o1; }
        if (base + 2 < n) { offs[base + 2] = o2; cursor[base + 2] = o2; }
        if (base + 3 < n) { offs[base + 3] = o3; cursor[base + 3] = o3; }
    }
}

// ================= bucket fill: ed[pos] = src only =================
__global__ void fill_kernel(const int* __restrict__ row, const int* __restrict__ col,
                            int* __restrict__ cursor, int* __restrict__ ed, int E) {
    int e = blockIdx.x * blockDim.x + threadIdx.x;
    if (e < E) {
        int c = col[e];
        int r = row[e];
        int pos = atomicAdd(&cursor[c], 1);
        ed[pos] = r;
    }
}

// ================= xws = (x @ W^T) * dis[row], stored bf16 =================
// MFMA 16x16x32 bf16. 128x128 tile per block, 4 waves, each wave 64x64
// (4m x 4n 16x16 tiles, 64 f32 acc). A-fragments straight from global
// (16 rows x 128 B contiguous per instruction pair -> full cache lines),
// converted f32->bf16 RNE in-register. W staged once in LDS as bf16 [o][k],
// row stride 136 (16 B aligned, 2-way banks only = free).
// A frag: A[m=lane&15][k=quad*8+j]; B frag from W[o][k] ("B^T input");
// C/D: col=lane&15, row=quad*4+reg (m89/m91-verified).
__global__ __launch_bounds__(256) void gemm_xws_kernel(const float* __restrict__ x,
                                                       const float* __restrict__ W,
                                                       const float* __restrict__ dis,
                                                       unsigned short* __restrict__ xws,
                                                       int n) {
    __shared__ short Wl[NF * WLD2];  // 34816 B

    for (int idx = threadIdx.x; idx < NF * 32; idx += 256) {
        int o = idx >> 5;
        int kq = (idx & 31) << 2;
        float4 v = *(const float4*)(W + o * NF + kq);
        short* d = &Wl[o * WLD2 + kq];
        d[0] = f2bf_rne(v.x); d[1] = f2bf_rne(v.y);
        d[2] = f2bf_rne(v.z); d[3] = f2bf_rne(v.w);
    }
    __syncthreads();

    const int lane = threadIdx.x & 63;
    const int wave = threadIdx.x >> 6;
    const int mhalf = (wave & 1) * 64;
    const int nhalf = (wave >> 1) * 64;
    const int l15 = lane & 15;
    const int quad = lane >> 4;
    const int tile = blockIdx.x * 128;

    f32x4 acc[4][4];
#pragma unroll
    for (int mb = 0; mb < 4; ++mb)
#pragma unroll
        for (int nb = 0; nb < 4; ++nb) acc[mb][nb] = (f32x4)0.0f;

#pragma unroll
    for (int kc = 0; kc < 4; ++kc) {
        const int kof = kc * 32 + quad * 8;
        bf16x8 Bf[4];
#pragma unroll
        for (int nb = 0; nb < 4; ++nb) {
            int o = nhalf + nb * 16 + l15;
            Bf[nb] = *(const bf16x8*)(&Wl[o * WLD2 + kof]);
        }
#pragma unroll
        for (int mb = 0; mb < 4; ++mb) {
            int r = tile + mhalf + mb * 16 + l15;
            if (r >= n) r = n - 1;  // clamp: duplicate row, stores masked below
            const float4* ap = (const float4*)(x + (size_t)r * NF + kof);
            float4 a0 = ap[0], a1 = ap[1];
            bf16x8 Af;
            Af[0] = f2bf_rne(a0.x); Af[1] = f2bf_rne(a0.y);
            Af[2] = f2bf_rne(a0.z); Af[3] = f2bf_rne(a0.w);
            Af[4] = f2bf_rne(a1.x); Af[5] = f2bf_rne(a1.y);
            Af[6] = f2bf_rne(a1.z); Af[7] = f2bf_rne(a1.w);
#pragma unroll
            for (int nb = 0; nb < 4; ++nb)
                acc[mb][nb] = __builtin_amdgcn_mfma_f32_16x16x32_bf16(Af, Bf[nb], acc[mb][nb], 0, 0, 0);
        }
    }

    // epilogue: scale rows by dis, convert bf16, store
#pragma unroll
    for (int mb = 0; mb < 4; ++mb) {
        int rbase = tile + mhalf + mb * 16 + quad * 4;
#pragma unroll
        for (int reg = 0; reg < 4; ++reg) {
            int r = rbase + reg;
            if (r < n) {
                float dsc = dis[r];
#pragma unroll
                for (int nb = 0; nb < 4; ++nb) {
                    int c = nhalf + nb * 16 + l15;
                    xws[(size_t)r * NF + c] = (unsigned short)f2bf_rne(acc[mb][nb][reg] * dsc);
                }
            }
        }
    }
}

// ================= gather: one wave per destination node =================
// xws rows are bf16 (256 B): lane reads one dword = 2 bf16. No per-edge norm:
// out[c] = dc * (sum_src xws[src] + xws[c]) + b
__global__ __launch_bounds__(256) void gather_kernel(const int* __restrict__ ed,
                                                     const int* __restrict__ offs,
                                                     const int* __restrict__ cnt,
                                                     const float* __restrict__ dis,
                                                     const unsigned* __restrict__ xws,
                                                     const float* __restrict__ b,
                                                     float* __restrict__ out, int n) {
    int node = (int)((blockIdx.x * blockDim.x + threadIdx.x) >> 6);
    int lane = threadIdx.x & 63;
    if (node >= n) return;
    float dc = dis[node];
    int start = offs[node];
    int end = start + cnt[node];
    float ax = 0.f, ay = 0.f;
    int i = start;
    for (; i + 4 <= end; i += 4) {
        int s0 = ed[i], s1 = ed[i + 1], s2 = ed[i + 2], s3 = ed[i + 3];
        unsigned u0 = xws[(size_t)s0 * 64 + lane];
        unsigned u1 = xws[(size_t)s1 * 64 + lane];
        unsigned u2 = xws[(size_t)s2 * 64 + lane];
        unsigned u3 = xws[(size_t)s3 * 64 + lane];
        ax += __uint_as_float(u0 << 16) + __uint_as_float(u1 << 16) +
              __uint_as_float(u2 << 16) + __uint_as_float(u3 << 16);
        ay += __uint_as_float(u0 & 0xFFFF0000u) + __uint_as_float(u1 & 0xFFFF0000u) +
              __uint_as_float(u2 & 0xFFFF0000u) + __uint_as_float(u3 & 0xFFFF0000u);
    }
    for (; i < end; ++i) {
        unsigned u = xws[(size_t)ed[i] * 64 + lane];
        ax += __uint_as_float(u << 16);
        ay += __uint_as_float(u & 0xFFFF0000u);
    }
    // self loop
    unsigned us = xws[(size_t)node * 64 + lane];
    ax += __uint_as_float(us << 16);
    ay += __uint_as_float(us & 0xFFFF0000u);
    float2 bb = ((const float2*)b)[lane];
    float2 o;
    o.x = fmaf(ax, dc, bb.x);
    o.y = fmaf(ay, dc, bb.y);
    ((float2*)(out + (size_t)node * NF))[lane] = o;
}

extern "C" void kernel_launch(void* const* d_in, const int* in_sizes, int n_in,
                              void* d_out, int out_size, void* d_ws, size_t ws_size,
                              hipStream_t stream) {
    const float* x = (const float*)d_in[0];
    const int* ei = (const int*)d_in[1];
    const float* W = (const float*)d_in[2];
    const float* b = (const float*)d_in[3];
    float* out = (float*)d_out;

    const int N = in_sizes[0] / NF;
    const int E = in_sizes[1] / 2;
    const int* row = ei;      // sources
    const int* col = ei + E;  // targets

    // workspace: xws [N*128 bf16] | cnt [N] | dis [N] | offs [N] | cursor [N] | ed [E int] | bsum
    char* ws = (char*)d_ws;
    unsigned short* xws = (unsigned short*)ws;
    ws += (size_t)N * NF * sizeof(unsigned short);
    int* cnt = (int*)ws; ws += (size_t)N * sizeof(int);
    float* dis = (float*)ws; ws += (size_t)N * sizeof(float);
    int* offs = (int*)ws; ws += (size_t)N * sizeof(int);
    int* cursor = (int*)ws; ws += (size_t)N * sizeof(int);
    int* ed = (int*)ws; ws += (size_t)E * sizeof(int);
    int* bsum = (int*)ws;

    const int B = (N + 1023) / 1024;  // 98 <= 256 (scan_bsums limit)

    // 1) count incoming edges (ws is poisoned each launch -> zero first)
    (void)hipMemsetAsync(cnt, 0, (size_t)N * sizeof(int), stream);
    count_kernel<<<(E + 255) / 256, 256, 0, stream>>>(col, cnt, E);

    // 2) dis = rsqrt(cnt + 1)
    dis_kernel<<<(N + 255) / 256, 256, 0, stream>>>(cnt, dis, N);

    // 3) exclusive scan cnt -> offs (+ cursor copy)
    scan_partials<<<B, 256, 0, stream>>>(cnt, bsum, N);
    scan_bsums<<<1, 256, 0, stream>>>(bsum, B);
    scan_final<<<B, 256, 0, stream>>>(cnt, bsum, offs, cursor, N);

    // 4) xws = (x @ W^T) * dis[row]  (bf16), MFMA
    gemm_xws_kernel<<<(N + 127) / 128, 256, 0, stream>>>(x, W, dis, xws, N);

    // 5) bucket fill (src only)
    fill_kernel<<<(E + 255) / 256, 256, 0, stream>>>(row, col, cursor, ed, E);

    // 6) gather + self loop + bias
    {
        int nodes_per_block = 256 / 64;
        int blocks = (N + nodes_per_block - 1) / nodes_per_block;
        gather_kernel<<<blocks, 256, 0, stream>>>(ed, offs, cnt, dis,
                                                  (const unsigned*)xws, b, out, N);
    }
}

// Round 7
// 320.564 us; speedup vs baseline: 5.4610x; 1.2468x over previous
//
#include <hip/hip_runtime.h>

#define NF 128    // feature dim (in == out == 128)
#define WLD2 136  // W LDS row stride in bf16 elems: 272 B -> 16B-aligned, 2-way banks only
#define NSLOT 8   // per-XCD histogram copies (blockIdx & 7 ~ XCD round-robin; perf-only assumption)

typedef __attribute__((ext_vector_type(8))) short bf16x8;
typedef __attribute__((ext_vector_type(4))) float f32x4;

__device__ inline short f2bf_rne(float f) {
    unsigned u = __float_as_uint(f);
    u += 0x7FFFu + ((u >> 16) & 1u);  // round-to-nearest-even (inputs finite)
    return (short)(u >> 16);
}

// ============ pass 1: slot-local histogram + per-edge rank ============
// slot = blockIdx&7 keeps the atomic's cache line in one XCD's L2 (no
// cross-XCD ownership ping-pong). rank written coalesced.
__global__ void count_rank_kernel(const int* __restrict__ col, int* __restrict__ cnt8,
                                  int* __restrict__ rank, int E, int N) {
    int e = blockIdx.x * blockDim.x + threadIdx.x;
    if (e < E) {
        int slot = blockIdx.x & (NSLOT - 1);
        rank[e] = atomicAdd(&cnt8[slot * N + col[e]], 1);
    }
}

// ============ reduce 8 copies -> cnt ============
__global__ void reduce_cnt_kernel(const int* __restrict__ cnt8, int* __restrict__ cnt, int N) {
    int i = blockIdx.x * blockDim.x + threadIdx.x;
    if (i < N) {
        int s = 0;
#pragma unroll
        for (int c = 0; c < NSLOT; ++c) s += cnt8[c * N + i];
        cnt[i] = s;
    }
}

__global__ void dis_kernel(const int* __restrict__ cnt, float* __restrict__ dis, int n) {
    int i = blockIdx.x * blockDim.x + threadIdx.x;
    if (i < n) dis[i] = rsqrtf((float)cnt[i] + 1.0f);  // +1: self loop
}

// ============ per-slot bases: base8[c][i] = offs[i] + sum_{c'<c} cnt8[c'][i] ============
__global__ void bases_kernel(const int* __restrict__ cnt8, const int* __restrict__ offs,
                             int* __restrict__ base8, int N) {
    int i = blockIdx.x * blockDim.x + threadIdx.x;
    if (i < N) {
        int b = offs[i];
#pragma unroll
        for (int c = 0; c < NSLOT; ++c) {
            base8[c * N + i] = b;
            b += cnt8[c * N + i];
        }
    }
}

// ================= exclusive scan over cnt -> offs =================
__device__ inline int block_exclusive_scan_256(int val) {
    __shared__ int wsum[4];
    int lane = threadIdx.x & 63, wave = threadIdx.x >> 6;
    int x = val;
#pragma unroll
    for (int off = 1; off < 64; off <<= 1) {
        int y = __shfl_up(x, off, 64);
        if (lane >= off) x += y;
    }
    if (lane == 63) wsum[wave] = x;
    __syncthreads();
    if (threadIdx.x == 0) {
        int acc = 0;
        for (int w = 0; w < 4; ++w) { int t = wsum[w]; wsum[w] = acc; acc += t; }
    }
    __syncthreads();
    return x - val + wsum[wave];
}

__global__ __launch_bounds__(256) void scan_partials(const int* __restrict__ cnt,
                                                     int* __restrict__ bsum, int n) {
    __shared__ int lds[4];
    int base = blockIdx.x * 1024;
    int s = 0;
    for (int i = threadIdx.x; i < 1024; i += 256) {
        int idx = base + i;
        if (idx < n) s += cnt[idx];
    }
#pragma unroll
    for (int off = 32; off > 0; off >>= 1) s += __shfl_down(s, off, 64);
    int lane = threadIdx.x & 63, wave = threadIdx.x >> 6;
    if (lane == 0) lds[wave] = s;
    __syncthreads();
    if (threadIdx.x == 0) bsum[blockIdx.x] = lds[0] + lds[1] + lds[2] + lds[3];
}

__global__ __launch_bounds__(256) void scan_bsums(int* __restrict__ bsum, int B) {
    int t = threadIdx.x;
    int v = (t < B) ? bsum[t] : 0;
    int exc = block_exclusive_scan_256(v);
    if (t < B) bsum[t] = exc;
}

__global__ __launch_bounds__(256) void scan_final(const int* __restrict__ cnt,
                                                  const int* __restrict__ bsum,
                                                  int* __restrict__ offs, int n) {
    int base = blockIdx.x * 1024 + threadIdx.x * 4;
    int v0 = 0, v1 = 0, v2 = 0, v3 = 0;
    if (base + 3 < n) {
        int4 v = *(const int4*)(cnt + base);
        v0 = v.x; v1 = v.y; v2 = v.z; v3 = v.w;
    } else {
        if (base + 0 < n) v0 = cnt[base + 0];
        if (base + 1 < n) v1 = cnt[base + 1];
        if (base + 2 < n) v2 = cnt[base + 2];
        if (base + 3 < n) v3 = cnt[base + 3];
    }
    int s = v0 + v1 + v2 + v3;
    int exc = block_exclusive_scan_256(s) + bsum[blockIdx.x];
    int o0 = exc, o1 = o0 + v0, o2 = o1 + v1, o3 = o2 + v2;
    if (base + 3 < n) {
        *(int4*)(offs + base) = make_int4(o0, o1, o2, o3);
    } else {
        if (base + 0 < n) offs[base + 0] = o0;
        if (base + 1 < n) offs[base + 1] = o1;
        if (base + 2 < n) offs[base + 2] = o2;
        if (base + 3 < n) offs[base + 3] = o3;
    }
}

// ============ atomic-free fill: pos = base8[slot][col] + rank ============
// base8 is read-only here -> lines replicate freely across XCD L2s.
// MUST use the same grid/block as count_rank so slot matches per edge.
__global__ void fill_kernel(const int* __restrict__ row, const int* __restrict__ col,
                            const int* __restrict__ rank, const int* __restrict__ base8,
                            int* __restrict__ ed, int E, int N) {
    int e = blockIdx.x * blockDim.x + threadIdx.x;
    if (e < E) {
        int slot = blockIdx.x & (NSLOT - 1);
        ed[base8[slot * N + col[e]] + rank[e]] = row[e];
    }
}

// ================= xws = (x @ W^T) * dis[row], stored bf16 =================
__global__ __launch_bounds__(256) void gemm_xws_kernel(const float* __restrict__ x,
                                                       const float* __restrict__ W,
                                                       const float* __restrict__ dis,
                                                       unsigned short* __restrict__ xws,
                                                       int n) {
    __shared__ short Wl[NF * WLD2];  // 34816 B

    for (int idx = threadIdx.x; idx < NF * 32; idx += 256) {
        int o = idx >> 5;
        int kq = (idx & 31) << 2;
        float4 v = *(const float4*)(W + o * NF + kq);
        short* d = &Wl[o * WLD2 + kq];
        d[0] = f2bf_rne(v.x); d[1] = f2bf_rne(v.y);
        d[2] = f2bf_rne(v.z); d[3] = f2bf_rne(v.w);
    }
    __syncthreads();

    const int lane = threadIdx.x & 63;
    const int wave = threadIdx.x >> 6;
    const int mhalf = (wave & 1) * 64;
    const int nhalf = (wave >> 1) * 64;
    const int l15 = lane & 15;
    const int quad = lane >> 4;
    const int tile = blockIdx.x * 128;

    f32x4 acc[4][4];
#pragma unroll
    for (int mb = 0; mb < 4; ++mb)
#pragma unroll
        for (int nb = 0; nb < 4; ++nb) acc[mb][nb] = (f32x4)0.0f;

#pragma unroll
    for (int kc = 0; kc < 4; ++kc) {
        const int kof = kc * 32 + quad * 8;
        bf16x8 Bf[4];
#pragma unroll
        for (int nb = 0; nb < 4; ++nb) {
            int o = nhalf + nb * 16 + l15;
            Bf[nb] = *(const bf16x8*)(&Wl[o * WLD2 + kof]);
        }
#pragma unroll
        for (int mb = 0; mb < 4; ++mb) {
            int r = tile + mhalf + mb * 16 + l15;
            if (r >= n) r = n - 1;  // clamp: duplicate row, stores masked below
            const float4* ap = (const float4*)(x + (size_t)r * NF + kof);
            float4 a0 = ap[0], a1 = ap[1];
            bf16x8 Af;
            Af[0] = f2bf_rne(a0.x); Af[1] = f2bf_rne(a0.y);
            Af[2] = f2bf_rne(a0.z); Af[3] = f2bf_rne(a0.w);
            Af[4] = f2bf_rne(a1.x); Af[5] = f2bf_rne(a1.y);
            Af[6] = f2bf_rne(a1.z); Af[7] = f2bf_rne(a1.w);
#pragma unroll
            for (int nb = 0; nb < 4; ++nb)
                acc[mb][nb] = __builtin_amdgcn_mfma_f32_16x16x32_bf16(Af, Bf[nb], acc[mb][nb], 0, 0, 0);
        }
    }

#pragma unroll
    for (int mb = 0; mb < 4; ++mb) {
        int rbase = tile + mhalf + mb * 16 + quad * 4;
#pragma unroll
        for (int reg = 0; reg < 4; ++reg) {
            int r = rbase + reg;
            if (r < n) {
                float dsc = dis[r];
#pragma unroll
                for (int nb = 0; nb < 4; ++nb) {
                    int c = nhalf + nb * 16 + l15;
                    xws[(size_t)r * NF + c] = (unsigned short)f2bf_rne(acc[mb][nb][reg] * dsc);
                }
            }
        }
    }
}

// ================= gather: one wave per destination node =================
// out[c] = dc * (sum_src xws[src] + xws[c]) + b
__global__ __launch_bounds__(256) void gather_kernel(const int* __restrict__ ed,
                                                     const int* __restrict__ offs,
                                                     const int* __restrict__ cnt,
                                                     const float* __restrict__ dis,
                                                     const unsigned* __restrict__ xws,
                                                     const float* __restrict__ b,
                                                     float* __restrict__ out, int n) {
    int node = (int)((blockIdx.x * blockDim.x + threadIdx.x) >> 6);
    int lane = threadIdx.x & 63;
    if (node >= n) return;
    float dc = dis[node];
    int start = offs[node];
    int end = start + cnt[node];
    float ax = 0.f, ay = 0.f;
    int i = start;
    for (; i + 4 <= end; i += 4) {
        int s0 = ed[i], s1 = ed[i + 1], s2 = ed[i + 2], s3 = ed[i + 3];
        unsigned u0 = xws[(size_t)s0 * 64 + lane];
        unsigned u1 = xws[(size_t)s1 * 64 + lane];
        unsigned u2 = xws[(size_t)s2 * 64 + lane];
        unsigned u3 = xws[(size_t)s3 * 64 + lane];
        ax += __uint_as_float(u0 << 16) + __uint_as_float(u1 << 16) +
              __uint_as_float(u2 << 16) + __uint_as_float(u3 << 16);
        ay += __uint_as_float(u0 & 0xFFFF0000u) + __uint_as_float(u1 & 0xFFFF0000u) +
              __uint_as_float(u2 & 0xFFFF0000u) + __uint_as_float(u3 & 0xFFFF0000u);
    }
    for (; i < end; ++i) {
        unsigned u = xws[(size_t)ed[i] * 64 + lane];
        ax += __uint_as_float(u << 16);
        ay += __uint_as_float(u & 0xFFFF0000u);
    }
    unsigned us = xws[(size_t)node * 64 + lane];
    ax += __uint_as_float(us << 16);
    ay += __uint_as_float(us & 0xFFFF0000u);
    float2 bb = ((const float2*)b)[lane];
    float2 o;
    o.x = fmaf(ax, dc, bb.x);
    o.y = fmaf(ay, dc, bb.y);
    ((float2*)(out + (size_t)node * NF))[lane] = o;
}

extern "C" void kernel_launch(void* const* d_in, const int* in_sizes, int n_in,
                              void* d_out, int out_size, void* d_ws, size_t ws_size,
                              hipStream_t stream) {
    const float* x = (const float*)d_in[0];
    const int* ei = (const int*)d_in[1];
    const float* W = (const float*)d_in[2];
    const float* b = (const float*)d_in[3];
    float* out = (float*)d_out;

    const int N = in_sizes[0] / NF;
    const int E = in_sizes[1] / 2;
    const int* row = ei;      // sources
    const int* col = ei + E;  // targets

    // workspace: xws [N*128 bf16] | cnt [N] | dis [N] | offs [N] | rank [E] |
    //            cnt8 [8N] | base8 [8N] | ed [E] | bsum
    char* ws = (char*)d_ws;
    unsigned short* xws = (unsigned short*)ws;
    ws += (size_t)N * NF * sizeof(unsigned short);
    int* cnt = (int*)ws; ws += (size_t)N * sizeof(int);
    float* dis = (float*)ws; ws += (size_t)N * sizeof(float);
    int* offs = (int*)ws; ws += (size_t)N * sizeof(int);
    int* rank = (int*)ws; ws += (size_t)E * sizeof(int);
    int* cnt8 = (int*)ws; ws += (size_t)NSLOT * N * sizeof(int);
    int* base8 = (int*)ws; ws += (size_t)NSLOT * N * sizeof(int);
    int* ed = (int*)ws; ws += (size_t)E * sizeof(int);
    int* bsum = (int*)ws;

    const int B = (N + 1023) / 1024;   // 98 <= 256 (scan_bsums limit)
    const int EG = (E + 255) / 256;    // shared grid for count_rank + fill (slot match)

    // 1) slot-local histogram + rank (cnt8 poisoned each launch -> zero first)
    (void)hipMemsetAsync(cnt8, 0, (size_t)NSLOT * N * sizeof(int), stream);
    count_rank_kernel<<<EG, 256, 0, stream>>>(col, cnt8, rank, E, N);

    // 2) cnt = sum of 8 copies; dis = rsqrt(cnt + 1)
    reduce_cnt_kernel<<<(N + 255) / 256, 256, 0, stream>>>(cnt8, cnt, N);
    dis_kernel<<<(N + 255) / 256, 256, 0, stream>>>(cnt, dis, N);

    // 3) exclusive scan cnt -> offs; per-slot bases
    scan_partials<<<B, 256, 0, stream>>>(cnt, bsum, N);
    scan_bsums<<<1, 256, 0, stream>>>(bsum, B);
    scan_final<<<B, 256, 0, stream>>>(cnt, bsum, offs, N);
    bases_kernel<<<(N + 255) / 256, 256, 0, stream>>>(cnt8, offs, base8, N);

    // 4) xws = (x @ W^T) * dis[row]  (bf16), MFMA
    gemm_xws_kernel<<<(N + 127) / 128, 256, 0, stream>>>(x, W, dis, xws, N);

    // 5) atomic-free bucket fill
    fill_kernel<<<EG, 256, 0, stream>>>(row, col, rank, base8, ed, E, N);

    // 6) gather + self loop + bias
    {
        int nodes_per_block = 256 / 64;
        int blocks = (N + nodes_per_block - 1) / nodes_per_block;
        gather_kernel<<<blocks, 256, 0, stream>>>(ed, offs, cnt, dis,
                                                  (const unsigned*)xws, b, out, N);
    }
}